// Round 11
// baseline (967.919 us; speedup 1.0000x reference)
//
#include <hip/hip_runtime.h>
#include <math.h>

#define R_NODES 1152
#define DIGITS 10
#define OUT_CH 16
#define IN_CH 8
#define BATCH 256
#define COLS 160            // DIGITS*OUT_CH
#define W_PER_R 1280        // DIGITS*OUT_CH*IN_CH
#define NSPLIT 288          // K-split: 4 r-rows per block
#define RPS 4               // rows per split
#define YBLK 8              // k_a batch blocks (32 b each)
#define WCPAD 36            // wc pair-stride (32 data + 4 pad)
#define AB_STRIDE (YBLK * R_NODES * DIGITS)   // 92160 floats per ab iteration-buffer

// ---------- s partials, k_a-style: W in REGISTERS, u broadcast from LDS ----------
// grid (288, 2): blockIdx.x = 4-row slice, blockIdx.y = 128-batch half.
// 256 thr = 8 groups of 32 lanes; group g owns batches g*16..g*16+15;
// lane tt owns 5 (d,o) pairs: pair = tt + 32k  (d = (tt>>4)+2k, o = tt&15).
// Wc (c-folded) staged once into a transposed+padded LDS buffer, then pulled
// into 160 regs/lane; inner loop = 8 broadcast b128 u-reads + 160 FMA + 5
// coalesced stores per batch. r6-r9 lesson: the old colgroup structure issued
// 48 LDS instrs per r-row per wave (LDS-bound at 2 waves/SIMD); this one is
// ~40:1 VALU:LDS, so 2 waves/SIMD of pure FMA saturate the SIMDs.
__global__ __launch_bounds__(256, 2) void k_s(
    const float* __restrict__ u,      // [B][R][8]
    const float* __restrict__ W,      // [R][10][16][8]
    const float* __restrict__ ab,     // [nbuf][YBLK][R][10] agreement partials
    float* __restrict__ part,         // [NSPLIT][B][160]
    float* __restrict__ sq,
    int nbuf)
{
    __shared__ float wc[COLS * WCPAD];   // 5760 floats = 23 KB, [pair][rr][i] pad 36
    __shared__ float ut[128 * 32];       // 4096 floats = 16 KB, [b][rr*8+i]
    __shared__ float cs[RPS * DIGITS];   // 40 logits -> c

    const int split = blockIdx.x;
    const int r0 = split * RPS;
    const int b0 = blockIdx.y * 128;
    const int t = threadIdx.x;
    const int tt = t & 31;
    const int grp = t >> 5;

    if (split == 0 && blockIdx.y == 0 && t == 0) *sq = 0.f;

    // ---- 1. issue u loads (4 f4/thread, coalesced 128B runs per batch)
    float4 ur[4]; int ub_[4], uq_[4];
#pragma unroll
    for (int p = 0; p < 4; ++p) {
        int idx = t + p * 256;            // 0..1023 f4 over 128 b x 32 floats
        int b = idx >> 3, q = idx & 7;
        ub_[p] = b; uq_[p] = q;
        ur[p] = ((const float4*)(u + (size_t)(b0 + b) * (R_NODES * IN_CH)
                                   + (size_t)r0 * IN_CH))[q];
    }
    // ---- 2. issue W loads (5 f4/thread, exact 1280 f4)
    float4 wr[5];
    {
        const float4* Wg = (const float4*)(W + (size_t)r0 * W_PER_R);
#pragma unroll
        for (int p = 0; p < 5; ++p) wr[p] = Wg[t + p * 256];
    }
    // ---- 3. write u tile (drains u only; W stays in flight)
#pragma unroll
    for (int p = 0; p < 4; ++p)
        *(float4*)&ut[ub_[p] * 32 + uq_[p] * 4] = ur[p];

    // ---- 4. c logits for rows r0..r0+3 (0 if nbuf==0 -> c = 0.1)
    if (t < RPS * DIGITS) {
        float a = 0.f;
        int r_l = t / 10, d = t - r_l * 10;
        const float* p0 = ab + (size_t)(r0 + r_l) * DIGITS + d;
        for (int bu = 0; bu < nbuf; ++bu)
#pragma unroll
            for (int yy = 0; yy < YBLK; ++yy)
                a += p0[(size_t)bu * AB_STRIDE + (size_t)yy * (R_NODES * DIGITS)];
        cs[t] = a;
    }
    __syncthreads();
    if (t < RPS) {
        float e[DIGITS];
        float m = -1e30f;
#pragma unroll
        for (int d = 0; d < DIGITS; ++d) m = fmaxf(m, cs[t*10 + d]);
        float ssum = 0.f;
#pragma unroll
        for (int d = 0; d < DIGITS; ++d) { e[d] = expf(cs[t*10 + d] - m); ssum += e[d]; }
        float inv = 1.f / ssum;
#pragma unroll
        for (int d = 0; d < DIGITS; ++d) cs[t*10 + d] = e[d] * inv;
    }
    __syncthreads();

    // ---- 5. fold c, transpose to [pair][rr][i] (pad 36), write LDS
#pragma unroll
    for (int p = 0; p < 5; ++p) {
        int e4 = t + p * 256;             // f4 idx 0..1279
        int rr = e4 / 320;                // 320 f4 per row
        int rem = e4 * 4 - rr * W_PER_R;
        int pair = rem >> 3;
        int i0 = (e4 & 1) * 4;
        float cv = cs[rr * 10 + (pair >> 4)];
        *(float4*)&wc[pair * WCPAD + rr * 8 + i0] =
            make_float4(wr[p].x * cv, wr[p].y * cv, wr[p].z * cv, wr[p].w * cv);
    }
    __syncthreads();

    // ---- 6. pull Wc into 160 regs/lane (one-time; 4-way conflict = 1.58x)
    float wcr[5][4][8];
#pragma unroll
    for (int k = 0; k < 5; ++k) {
        int pair = tt + 32 * k;
#pragma unroll
        for (int rr = 0; rr < RPS; ++rr) {
            float4 a0 = *(const float4*)&wc[pair * WCPAD + rr * 8];
            float4 a1 = *(const float4*)&wc[pair * WCPAD + rr * 8 + 4];
            wcr[k][rr][0]=a0.x; wcr[k][rr][1]=a0.y; wcr[k][rr][2]=a0.z; wcr[k][rr][3]=a0.w;
            wcr[k][rr][4]=a1.x; wcr[k][rr][5]=a1.y; wcr[k][rr][6]=a1.z; wcr[k][rr][7]=a1.w;
        }
    }

    // ---- 7. inner loop: per batch, 8 broadcast b128 + 160 FMA + 5 stores
    float* pp = part + (size_t)split * (BATCH * COLS) + (size_t)b0 * COLS;
#pragma unroll 2
    for (int bi = 0; bi < 16; ++bi) {
        const int bl = grp * 16 + bi;
        const float* up = &ut[bl * 32];
        float uu[4][8];
#pragma unroll
        for (int rr = 0; rr < RPS; ++rr) {
            float4 a0 = *(const float4*)(up + rr * 8);
            float4 a1 = *(const float4*)(up + rr * 8 + 4);
            uu[rr][0]=a0.x; uu[rr][1]=a0.y; uu[rr][2]=a0.z; uu[rr][3]=a0.w;
            uu[rr][4]=a1.x; uu[rr][5]=a1.y; uu[rr][6]=a1.z; uu[rr][7]=a1.w;
        }
        float* row = pp + (size_t)bl * COLS + tt;
#pragma unroll
        for (int k = 0; k < 5; ++k) {
            float a = 0.f;
#pragma unroll
            for (int rr = 0; rr < RPS; ++rr) {
                a = fmaf(wcr[k][rr][0], uu[rr][0], a);
                a = fmaf(wcr[k][rr][1], uu[rr][1], a);
                a = fmaf(wcr[k][rr][2], uu[rr][2], a);
                a = fmaf(wcr[k][rr][3], uu[rr][3], a);
                a = fmaf(wcr[k][rr][4], uu[rr][4], a);
                a = fmaf(wcr[k][rr][5], uu[rr][5], a);
                a = fmaf(wcr[k][rr][6], uu[rr][6], a);
                a = fmaf(wcr[k][rr][7], uu[rr][7], a);
            }
            row[32 * k] = a;
        }
    }
}

// ---------- reduce partials -> s ; accumulate global sum of squares ----------
__global__ void k_sq(const float* __restrict__ part,
                     float* __restrict__ s,
                     float* __restrict__ sq)
{
    const int t = threadIdx.x;
    const int e0 = blockIdx.x * 64;
    const int el = t & 63, q = t >> 6;
    float v = 0.f;
    for (int sp = q; sp < NSPLIT; sp += 4)
        v += part[(size_t)sp * (BATCH * COLS) + e0 + el];
    __shared__ float red[256];
    red[t] = v;
    __syncthreads();
    if (t < 64) {
        float vv = red[t] + red[t + 64] + red[t + 128] + red[t + 192];
        s[e0 + t] = vv;
        float x = vv * vv;
#pragma unroll
        for (int off = 32; off > 0; off >>= 1)
            x += __shfl_down(x, off, 64);
        if (t == 0) atomicAdd(sq, x);
    }
}

// ---------- agreement partials: ab[y][r,d] = scale * sum_{b in y,o} u_hat*s ----------
__global__ __launch_bounds__(256) void k_a(
    const float* __restrict__ u,
    const float* __restrict__ W,
    const float* __restrict__ s,
    const float* __restrict__ sq,
    float* __restrict__ ab)
{
    __shared__ float st[32 * COLS];   // 20.5 KB
    __shared__ float ut[32 * 64];     // 8 KB
    const int t = threadIdx.x;
    const int rblk = blockIdx.x;
    const int r = rblk * 8 + (t >> 5);
    const int tt = t & 31;
    const int bstart = blockIdx.y * 32;

    {
        const float4* sp = (const float4*)(s + (size_t)bstart * COLS);
#pragma unroll
        for (int p = 0; p < 5; ++p) ((float4*)st)[t + p * 256] = sp[t + p * 256];
    }
#pragma unroll
    for (int p = 0; p < 2; ++p) {
        int idx = t + p * 256;
        int bb = idx >> 4, qq = idx & 15;
        ((float4*)ut)[idx] =
            ((const float4*)(u + (size_t)(bstart + bb) * (R_NODES*IN_CH) + (size_t)rblk * 64))[qq];
    }

    float wreg[5][8];
#pragma unroll
    for (int k = 0; k < 5; ++k) {
        const float4* wp = (const float4*)(W + (size_t)r * W_PER_R + (size_t)(tt + 32*k) * IN_CH);
        float4 w0 = wp[0], w1 = wp[1];
        wreg[k][0]=w0.x; wreg[k][1]=w0.y; wreg[k][2]=w0.z; wreg[k][3]=w0.w;
        wreg[k][4]=w1.x; wreg[k][5]=w1.y; wreg[k][6]=w1.z; wreg[k][7]=w1.w;
    }
    __syncthreads();

    float acc[5] = {0.f, 0.f, 0.f, 0.f, 0.f};
#pragma unroll 2
    for (int b = 0; b < 32; ++b) {
        const float* ub = &ut[b * 64 + (t >> 5) * 8];
        float4 a0 = *(const float4*)ub;
        float4 a1 = *(const float4*)(ub + 4);
        const float* sb = &st[b * COLS];
#pragma unroll
        for (int k = 0; k < 5; ++k) {
            float vv = sb[tt + 32*k];
            float uh;
            uh = wreg[k][0] * a0.x;
            uh = fmaf(wreg[k][1], a0.y, uh);
            uh = fmaf(wreg[k][2], a0.z, uh);
            uh = fmaf(wreg[k][3], a0.w, uh);
            uh = fmaf(wreg[k][4], a1.x, uh);
            uh = fmaf(wreg[k][5], a1.y, uh);
            uh = fmaf(wreg[k][6], a1.z, uh);
            uh = fmaf(wreg[k][7], a1.w, uh);
            acc[k] = fmaf(uh, vv, acc[k]);
        }
    }
    float q = *sq;
    float scale = sqrtf(q) / (1.f + q);
    float* abp = ab + (size_t)blockIdx.y * (R_NODES * DIGITS) + r * DIGITS;
#pragma unroll
    for (int k = 0; k < 5; ++k) {
        float x = acc[k] * scale;
        x += __shfl_xor(x, 1, 64);
        x += __shfl_xor(x, 2, 64);
        x += __shfl_xor(x, 4, 64);
        x += __shfl_xor(x, 8, 64);
        if ((tt & 15) == 0) {
            int d = (tt >> 4) + 2*k;
            abp[d] = x;
        }
    }
}

// ---------- final output: v = s * sqrt(sq)/(1+sq) ----------
__global__ void k_scale(const float* __restrict__ s,
                        const float* __restrict__ sq,
                        float* __restrict__ out)
{
    int e = blockIdx.x * 256 + threadIdx.x;
    float q = *sq;
    float scale = sqrtf(q) / (1.f + q);
    out[e] = s[e] * scale;
}

extern "C" void kernel_launch(void* const* d_in, const int* in_sizes, int n_in,
                              void* d_out, int out_size, void* d_ws, size_t ws_size,
                              hipStream_t stream)
{
    const float* u = (const float*)d_in[0];   // (256, 1152, 8)
    const float* W = (const float*)d_in[1];   // (1, 1152, 10, 16, 8)
    float* out = (float*)d_out;               // (256, 10, 16)
    float* ws = (float*)d_ws;

    float* s    = ws;                          // 40960 floats
    float* sq   = ws + 40960;                  // 1 (padded to 64)
    float* ab   = ws + 41024;                  // 2 * 92160
    float* part = ws + 41024 + 2 * AB_STRIDE;  // 288 * 40960 (~47 MB; ws is 256 MiB)

    for (int it = 0; it < 3; ++it) {
        k_s<<<dim3(NSPLIT, 2), dim3(256), 0, stream>>>(u, W, ab, part, sq, it);
        k_sq<<<dim3(BATCH * COLS / 64), dim3(256), 0, stream>>>(part, s, sq);
        if (it < 2)
            k_a<<<dim3(R_NODES / 8, YBLK), dim3(256), 0, stream>>>(u, W, s, sq,
                                                                   ab + (size_t)it * AB_STRIDE);
        else
            k_scale<<<dim3(BATCH * COLS / 256), dim3(256), 0, stream>>>(s, sq, out);
    }
}

// Round 12
// 161.913 us; speedup vs baseline: 5.9780x; 5.9780x over previous
//
#include <hip/hip_runtime.h>
#include <math.h>

#define R_NODES 1152
#define DIGITS 10
#define OUT_CH 16
#define IN_CH 8
#define BATCH 256
#define COLS 160            // DIGITS*OUT_CH
#define W_PER_R 1280        // DIGITS*OUT_CH*IN_CH
#define NSPLIT 192          // K-split: 6 r-rows per block
#define RPS 6               // rows per split
#define YBLK 8              // k_a batch blocks (32 b each)
#define UPAD 52             // u-LDS batch stride (48 data + 4 pad): 2-way alias = free
#define AB_STRIDE (YBLK * R_NODES * DIGITS)   // 92160 floats per ab iteration-buffer

// ---------- s partials: o-lane layout, W global->regs (L1), u via LDS ----------
// grid (192, 4): blockIdx.x = 6-row slice, blockIdx.y = 64-batch block.
// 256 thr = 16 o-lanes x 16 bs; lane owns output cols (d,o) for d=0..9 and
// batches bs+16*jj (jj=0..3) -> acc[4][10].
// r11 lesson: >80-float reg tiles spill (160-float wcr -> scratch, 5x slower).
// r6-r9 lesson: the 10-float colgroup LDS stride forced 44 LDS instr per r_l
// per wave (LDS-pipe-bound ~2100 cyc/wave). Here W[r][d][o][0..7] is read as
// 2 global dwordx4 (16 unique 16B segs/instr, L1-broadcast over bs-lanes, slice
// L1-resident), u broadcast from a small LDS tile: 8 LDS instr per r_l per wave
// vs 360 FMA -> VALU-bound (floor ~5.4us).
__global__ __launch_bounds__(256, 4) void k_s(
    const float* __restrict__ u,      // [B][R][8]
    const float* __restrict__ W,      // [R][10][16][8]
    const float* __restrict__ ab,     // [nbuf][YBLK][R][10] agreement partials
    float* __restrict__ part,         // [NSPLIT][B][160]
    float* __restrict__ sq,
    int nbuf)
{
    __shared__ float ut[64 * UPAD];     // 13,312 B
    __shared__ float cs[RPS * DIGITS];  // c for this block's 6 rows

    const int split = blockIdx.x;
    const int b0 = blockIdx.y * 64;
    const int t = threadIdx.x;
    const int o = t & 15;
    const int bs = t >> 4;
    const int r0 = split * RPS;

    if (split == 0 && blockIdx.y == 0 && t == 0) *sq = 0.f;

    // ---- 1. stage u-tile (3 float4/thread, coalesced 192B runs per batch)
    float4 ur[3]; int ub_[3], uq_[3];
#pragma unroll
    for (int p = 0; p < 3; ++p) {
        int idx = t + p * 256;            // 0..767
        int b = idx / 12, q = idx - b * 12;   // batch 0..63, float4 0..11
        ub_[p] = b; uq_[p] = q;
        ur[p] = ((const float4*)(u + (size_t)(b0 + b) * (R_NODES * IN_CH)
                                   + (size_t)r0 * IN_CH))[q];
    }
#pragma unroll
    for (int p = 0; p < 3; ++p)
        *(float4*)&ut[ub_[p] * UPAD + uq_[p] * 4] = ur[p];

    // ---- 2. c logits for rows r0..r0+5 (0 if nbuf==0 -> softmax = 0.1)
    if (t < RPS * DIGITS) {
        float a = 0.f;
        int r_l = t / 10, d = t - r_l * 10;
        const float* p0 = ab + (size_t)(r0 + r_l) * DIGITS + d;
        for (int bu = 0; bu < nbuf; ++bu)
#pragma unroll
            for (int yy = 0; yy < YBLK; ++yy)
                a += p0[(size_t)bu * AB_STRIDE + (size_t)yy * (R_NODES * DIGITS)];
        cs[t] = a;
    }
    __syncthreads();
    if (t < RPS) {
        float e[DIGITS];
        float m = -1e30f;
#pragma unroll
        for (int d = 0; d < DIGITS; ++d) m = fmaxf(m, cs[t*10 + d]);
        float ssum = 0.f;
#pragma unroll
        for (int d = 0; d < DIGITS; ++d) { e[d] = expf(cs[t*10 + d] - m); ssum += e[d]; }
        float inv = 1.f / ssum;
#pragma unroll
        for (int d = 0; d < DIGITS; ++d) cs[t*10 + d] = e[d] * inv;
    }
    __syncthreads();

    // ---- 3. main loop: u broadcast from LDS, W streamed global->regs (L1)
    float acc[4][10];
#pragma unroll
    for (int jj = 0; jj < 4; ++jj)
#pragma unroll
        for (int j = 0; j < 10; ++j) acc[jj][j] = 0.f;

    const float* Wb = W + (size_t)r0 * W_PER_R + (size_t)o * IN_CH;

    for (int r_l = 0; r_l < RPS; ++r_l) {
        float4 ua[4], ub2[4];
#pragma unroll
        for (int jj = 0; jj < 4; ++jj) {
            const float* up = &ut[(bs + jj * 16) * UPAD + r_l * 8];
            ua[jj]  = *(const float4*)up;
            ub2[jj] = *(const float4*)(up + 4);
        }
        const float* Wr = Wb + (size_t)r_l * W_PER_R;
#pragma unroll
        for (int d = 0; d < 10; ++d) {
            const float4* wp = (const float4*)(Wr + d * 128);
            float4 w0 = wp[0], w1 = wp[1];
            float cv = cs[r_l * 10 + d];
#pragma unroll
            for (int jj = 0; jj < 4; ++jj) {
                float uh;
                uh = w0.x * ua[jj].x;
                uh = fmaf(w0.y, ua[jj].y, uh);
                uh = fmaf(w0.z, ua[jj].z, uh);
                uh = fmaf(w0.w, ua[jj].w, uh);
                uh = fmaf(w1.x, ub2[jj].x, uh);
                uh = fmaf(w1.y, ub2[jj].y, uh);
                uh = fmaf(w1.z, ub2[jj].z, uh);
                uh = fmaf(w1.w, ub2[jj].w, uh);
                acc[jj][d] = fmaf(uh, cv, acc[jj][d]);
            }
        }
    }

    // ---- 4. store: part[split][b0+bs+16jj][d*16+o]
    float* pp = part + (size_t)split * (BATCH * COLS) + (size_t)b0 * COLS;
#pragma unroll
    for (int jj = 0; jj < 4; ++jj) {
        float* row = pp + (size_t)(bs + jj * 16) * COLS + o;
#pragma unroll
        for (int d = 0; d < 10; ++d) row[d * 16] = acc[jj][d];
    }
}

// ---------- reduce partials -> s ; accumulate global sum of squares ----------
__global__ void k_sq(const float* __restrict__ part,
                     float* __restrict__ s,
                     float* __restrict__ sq)
{
    const int t = threadIdx.x;
    const int e0 = blockIdx.x * 64;
    const int el = t & 63, q = t >> 6;
    float v = 0.f;
    for (int sp = q; sp < NSPLIT; sp += 4)
        v += part[(size_t)sp * (BATCH * COLS) + e0 + el];
    __shared__ float red[256];
    red[t] = v;
    __syncthreads();
    if (t < 64) {
        float vv = red[t] + red[t + 64] + red[t + 128] + red[t + 192];
        s[e0 + t] = vv;
        float x = vv * vv;
#pragma unroll
        for (int off = 32; off > 0; off >>= 1)
            x += __shfl_down(x, off, 64);
        if (t == 0) atomicAdd(sq, x);
    }
}

// ---------- agreement partials: ab[y][r,d] = scale * sum_{b in y,o} u_hat*s ----------
__global__ __launch_bounds__(256) void k_a(
    const float* __restrict__ u,
    const float* __restrict__ W,
    const float* __restrict__ s,
    const float* __restrict__ sq,
    float* __restrict__ ab)
{
    __shared__ float st[32 * COLS];   // 20.5 KB
    __shared__ float ut[32 * 64];     // 8 KB
    const int t = threadIdx.x;
    const int rblk = blockIdx.x;
    const int r = rblk * 8 + (t >> 5);
    const int tt = t & 31;
    const int bstart = blockIdx.y * 32;

    {
        const float4* sp = (const float4*)(s + (size_t)bstart * COLS);
#pragma unroll
        for (int p = 0; p < 5; ++p) ((float4*)st)[t + p * 256] = sp[t + p * 256];
    }
#pragma unroll
    for (int p = 0; p < 2; ++p) {
        int idx = t + p * 256;
        int bb = idx >> 4, qq = idx & 15;
        ((float4*)ut)[idx] =
            ((const float4*)(u + (size_t)(bstart + bb) * (R_NODES*IN_CH) + (size_t)rblk * 64))[qq];
    }

    float wreg[5][8];
#pragma unroll
    for (int k = 0; k < 5; ++k) {
        const float4* wp = (const float4*)(W + (size_t)r * W_PER_R + (size_t)(tt + 32*k) * IN_CH);
        float4 w0 = wp[0], w1 = wp[1];
        wreg[k][0]=w0.x; wreg[k][1]=w0.y; wreg[k][2]=w0.z; wreg[k][3]=w0.w;
        wreg[k][4]=w1.x; wreg[k][5]=w1.y; wreg[k][6]=w1.z; wreg[k][7]=w1.w;
    }
    __syncthreads();

    float acc[5] = {0.f, 0.f, 0.f, 0.f, 0.f};
#pragma unroll 2
    for (int b = 0; b < 32; ++b) {
        const float* ub = &ut[b * 64 + (t >> 5) * 8];
        float4 a0 = *(const float4*)ub;
        float4 a1 = *(const float4*)(ub + 4);
        const float* sb = &st[b * COLS];
#pragma unroll
        for (int k = 0; k < 5; ++k) {
            float vv = sb[tt + 32*k];
            float uh;
            uh = wreg[k][0] * a0.x;
            uh = fmaf(wreg[k][1], a0.y, uh);
            uh = fmaf(wreg[k][2], a0.z, uh);
            uh = fmaf(wreg[k][3], a0.w, uh);
            uh = fmaf(wreg[k][4], a1.x, uh);
            uh = fmaf(wreg[k][5], a1.y, uh);
            uh = fmaf(wreg[k][6], a1.z, uh);
            uh = fmaf(wreg[k][7], a1.w, uh);
            acc[k] = fmaf(uh, vv, acc[k]);
        }
    }
    float q = *sq;
    float scale = sqrtf(q) / (1.f + q);
    float* abp = ab + (size_t)blockIdx.y * (R_NODES * DIGITS) + r * DIGITS;
#pragma unroll
    for (int k = 0; k < 5; ++k) {
        float x = acc[k] * scale;
        x += __shfl_xor(x, 1, 64);
        x += __shfl_xor(x, 2, 64);
        x += __shfl_xor(x, 4, 64);
        x += __shfl_xor(x, 8, 64);
        if ((tt & 15) == 0) {
            int d = (tt >> 4) + 2*k;
            abp[d] = x;
        }
    }
}

// ---------- final output: v = s * sqrt(sq)/(1+sq) ----------
__global__ void k_scale(const float* __restrict__ s,
                        const float* __restrict__ sq,
                        float* __restrict__ out)
{
    int e = blockIdx.x * 256 + threadIdx.x;
    float q = *sq;
    float scale = sqrtf(q) / (1.f + q);
    out[e] = s[e] * scale;
}

extern "C" void kernel_launch(void* const* d_in, const int* in_sizes, int n_in,
                              void* d_out, int out_size, void* d_ws, size_t ws_size,
                              hipStream_t stream)
{
    const float* u = (const float*)d_in[0];   // (256, 1152, 8)
    const float* W = (const float*)d_in[1];   // (1, 1152, 10, 16, 8)
    float* out = (float*)d_out;               // (256, 10, 16)
    float* ws = (float*)d_ws;

    float* s    = ws;                          // 40960 floats
    float* sq   = ws + 40960;                  // 1 (padded to 64)
    float* ab   = ws + 41024;                  // 2 * 92160
    float* part = ws + 41024 + 2 * AB_STRIDE;  // 192 * 40960 (~31.5 MB; ws is 256 MiB)

    for (int it = 0; it < 3; ++it) {
        k_s<<<dim3(NSPLIT, 4), dim3(256), 0, stream>>>(u, W, ab, part, sq, it);
        k_sq<<<dim3(BATCH * COLS / 64), dim3(256), 0, stream>>>(part, s, sq);
        if (it < 2)
            k_a<<<dim3(R_NODES / 8, YBLK), dim3(256), 0, stream>>>(u, W, s, sq,
                                                                   ab + (size_t)it * AB_STRIDE);
        else
            k_scale<<<dim3(BATCH * COLS / 256), dim3(256), 0, stream>>>(s, sq, out);
    }
}